// Round 2
// baseline (363.712 us; speedup 1.0000x reference)
//
#include <hip/hip_runtime.h>
#include <math.h>

namespace {
constexpr int B = 512, S = 64, K = 8, D = 16, NR = 64, NSTEPS = 100, NUNITS = 128;
}

// ---------------------------------------------------------------------------
// Diffusion alpha schedule: betas = sigmoid(linspace(-6,6,100))*(0.005-1e-5)+1e-5
// aprod = cumprod(1-betas); sa = sqrt(aprod), so = sqrt(1-aprod)
// Each thread i recomputes the serial cumprod up to i (exactly matches ref order).
// ---------------------------------------------------------------------------
__global__ void k_sched(float* __restrict__ sa, float* __restrict__ so) {
    int i = threadIdx.x;
    if (i < NSTEPS) {
        float prod = 1.0f;
        for (int jj = 0; jj <= i; ++jj) {
            float x = -6.0f + (float)jj * (12.0f / 99.0f);
            float sig = 1.0f / (1.0f + expf(-x));
            float beta = sig * (0.005f - 1e-5f) + 1e-5f;
            prod *= (1.0f - beta);
        }
        sa[i] = sqrtf(prod);
        so[i] = sqrtf(1.0f - prod);
    }
}

// ---------------------------------------------------------------------------
// w[b][r] = mean_d( usr_emb[u[b]][d] * rel_emb[r][d] )
// ---------------------------------------------------------------------------
__global__ void k_userrel(const float* __restrict__ usr_emb,
                          const float* __restrict__ rel_emb,
                          const int* __restrict__ u,
                          float* __restrict__ w) {
    int b = blockIdx.x, r = threadIdx.x;   // 512 blocks x 64 threads
    const float* ur = usr_emb + (long)u[b] * D;
    const float* rr = rel_emb + r * D;
    float s = 0.f;
#pragma unroll
    for (int d = 0; d < D; ++d) s += ur[d] * rr[d];
    w[b * NR + r] = s * (1.0f / (float)D);
}

// ---------------------------------------------------------------------------
// KGCN: one 64-lane wave per (b,s) pair; 4 pairs per 256-thread block.
// Lane = (k,j): owns level-2 neighbor e2[k][j].
// ---------------------------------------------------------------------------
__global__ __launch_bounds__(256) void k_kgcn(
    const float* __restrict__ ent_emb,
    const float* __restrict__ w_tab,      // [B, NR]
    const int* __restrict__ click_seq,    // [B*S]
    const int* __restrict__ adj_ent,      // [NE, K]
    const int* __restrict__ adj_rel,      // [NE, K]
    const float* __restrict__ agg_W,      // [D, D]
    const float* __restrict__ agg_b,      // [D]
    float* __restrict__ item)             // [B*S, D]
{
    __shared__ float wb[NR];
    __shared__ float Ws[D][D + 1];
    __shared__ float bs[D];
    __shared__ float Ms[4][K][D + 1];
    __shared__ float h1s[4][K][D + 1];
    __shared__ float h0s[4][D];

    const int tid = threadIdx.x;
    const int pg = tid >> 6;            // pair-in-block 0..3
    const int lane = tid & 63;
    const int p = blockIdx.x * 4 + pg;  // pair id = b*S + s
    const int b = blockIdx.x >> 4;      // 4 pairs/block, 64 pairs/b -> same b per block

    // ---- cooperative LDS staging (blockDim = 256; conditions NON-exclusive)
    // BUG FIX (R1): previous version only loaded Ws rows 0..11 and never
    // loaded bs (conditions assumed >=336 threads). Now: all 256 threads
    // load the full 16x16 agg_W; tid<64 loads wb; tid<16 loads agg_b.
    Ws[tid >> 4][tid & 15] = agg_W[tid];
    if (tid < NR) wb[tid] = w_tab[b * NR + tid];
    if (tid < D) bs[tid] = agg_b[tid];
    __syncthreads();

    const int k = lane >> 3, j = lane & 7;
    const int e0 = click_seq[p];
    const int e1k = adj_ent[(long)e0 * K + k];
    const int e2kj = adj_ent[(long)e1k * K + j];
    const int r1kj = adj_rel[(long)e1k * K + j];
    const int r0k = adj_rel[(long)e0 * K + k];

    // ---- hop-1 softmax over j (within 8-lane groups; xor masks 1,2,4 stay in-group)
    float s1 = wb[r1kj];
    float m1 = s1;
    m1 = fmaxf(m1, __shfl_xor(m1, 1));
    m1 = fmaxf(m1, __shfl_xor(m1, 2));
    m1 = fmaxf(m1, __shfl_xor(m1, 4));
    float ex = expf(s1 - m1);
    float den = ex;
    den += __shfl_xor(den, 1);
    den += __shfl_xor(den, 2);
    den += __shfl_xor(den, 4);
    float p1 = ex / den;

    // ---- gather q2 row (64 B), weight by p1, butterfly-reduce over j
    float agg[D];
    {
        const float4* q2p = (const float4*)(ent_emb + (long)e2kj * D);
        float4 a0 = q2p[0], a1 = q2p[1], a2 = q2p[2], a3 = q2p[3];
        agg[0] = p1 * a0.x;  agg[1] = p1 * a0.y;  agg[2] = p1 * a0.z;  agg[3] = p1 * a0.w;
        agg[4] = p1 * a1.x;  agg[5] = p1 * a1.y;  agg[6] = p1 * a1.z;  agg[7] = p1 * a1.w;
        agg[8] = p1 * a2.x;  agg[9] = p1 * a2.y;  agg[10] = p1 * a2.z; agg[11] = p1 * a2.w;
        agg[12] = p1 * a3.x; agg[13] = p1 * a3.y; agg[14] = p1 * a3.z; agg[15] = p1 * a3.w;
    }
#pragma unroll
    for (int m = 1; m <= 4; m <<= 1)
#pragma unroll
        for (int d = 0; d < D; ++d) agg[d] += __shfl_xor(agg[d], m);

    // ---- q1 row (broadcast across the 8 lanes of the group)
    float q1[D];
    {
        const float4* q1p = (const float4*)(ent_emb + (long)e1k * D);
        float4 a0 = q1p[0], a1 = q1p[1], a2 = q1p[2], a3 = q1p[3];
        q1[0] = a0.x;  q1[1] = a0.y;  q1[2] = a0.z;  q1[3] = a0.w;
        q1[4] = a1.x;  q1[5] = a1.y;  q1[6] = a1.z;  q1[7] = a1.w;
        q1[8] = a2.x;  q1[9] = a2.y;  q1[10] = a2.z; q1[11] = a2.w;
        q1[12] = a3.x; q1[13] = a3.y; q1[14] = a3.z; q1[15] = a3.w;
    }
    // M[k] = self(q1) + neigh_agg  (lane j writes elements 2j, 2j+1)
    Ms[pg][k][2 * j]     = q1[2 * j]     + agg[2 * j];
    Ms[pg][k][2 * j + 1] = q1[2 * j + 1] + agg[2 * j + 1];
    __syncthreads();

    // ---- h1[k] = sigmoid(M[k] @ W + b); 128 outputs over 64 lanes (2 each)
#pragma unroll
    for (int o = lane; o < 128; o += 64) {
        int ko = o >> 4, dd = o & 15;
        float acc = bs[dd];
#pragma unroll
        for (int din = 0; din < D; ++din) acc += Ms[pg][ko][din] * Ws[din][dd];
        h1s[pg][ko][dd] = 1.0f / (1.0f + expf(-acc));
    }

    // ---- hop-0 softmax over k (xor masks 8,16,32 keep j fixed)
    float s0 = wb[r0k];
    float m0 = s0;
    m0 = fmaxf(m0, __shfl_xor(m0, 8));
    m0 = fmaxf(m0, __shfl_xor(m0, 16));
    m0 = fmaxf(m0, __shfl_xor(m0, 32));
    float e0x = expf(s0 - m0);
    float d0 = e0x;
    d0 += __shfl_xor(d0, 8);
    d0 += __shfl_xor(d0, 16);
    d0 += __shfl_xor(d0, 32);
    float p0 = e0x / d0;

    // ---- agg0 = sum_k p0_k * q1[k]  (butterfly over k)
    float ag0[D];
#pragma unroll
    for (int d = 0; d < D; ++d) ag0[d] = p0 * q1[d];
#pragma unroll
    for (int m = 8; m <= 32; m <<= 1)
#pragma unroll
        for (int d = 0; d < D; ++d) ag0[d] += __shfl_xor(ag0[d], m);

    // ---- q0 row; h0 = sigmoid((q0 + agg0) @ W + b) (each lane computes dout = lane&15)
    float q0v[D];
    {
        const float4* q0p = (const float4*)(ent_emb + (long)e0 * D);
        float4 a0 = q0p[0], a1 = q0p[1], a2 = q0p[2], a3 = q0p[3];
        q0v[0] = a0.x;  q0v[1] = a0.y;  q0v[2] = a0.z;  q0v[3] = a0.w;
        q0v[4] = a1.x;  q0v[5] = a1.y;  q0v[6] = a1.z;  q0v[7] = a1.w;
        q0v[8] = a2.x;  q0v[9] = a2.y;  q0v[10] = a2.z; q0v[11] = a2.w;
        q0v[12] = a3.x; q0v[13] = a3.y; q0v[14] = a3.z; q0v[15] = a3.w;
    }
    const int ddl = lane & 15;
    float acc0 = bs[ddl];
#pragma unroll
    for (int din = 0; din < D; ++din) acc0 += (q0v[din] + ag0[din]) * Ws[din][ddl];
    float h0v = 1.0f / (1.0f + expf(-acc0));
    if (lane < 16) h0s[pg][lane] = h0v;
    __syncthreads();   // h1s + h0s now visible

    // ---- iteration 1 (tanh): agg1 = sum_k p0_k * h1[k]; same p0 (rel/user unchanged)
    float ag1[D];
#pragma unroll
    for (int d = 0; d < D; ++d) ag1[d] = p0 * h1s[pg][k][d];
#pragma unroll
    for (int m = 8; m <= 32; m <<= 1)
#pragma unroll
        for (int d = 0; d < D; ++d) ag1[d] += __shfl_xor(ag1[d], m);

    float acc1 = bs[ddl];
#pragma unroll
    for (int din = 0; din < D; ++din) acc1 += (h0s[pg][din] + ag1[din]) * Ws[din][ddl];
    float fin = tanhf(acc1);
    if (lane < 16) item[(long)p * D + lane] = fmaxf(fin, 0.0f);
}

// ---------------------------------------------------------------------------
// Per-b fusion head: sum/max over S, fc1 (32->64), fc2 (64->16), dot ent_emb[v]
// ---------------------------------------------------------------------------
__global__ __launch_bounds__(64) void k_fuse(
    const float* __restrict__ item,     // [B*S, D]
    const float* __restrict__ fc1_W,    // [32, 64]
    const float* __restrict__ fc1_b,    // [64]
    const float* __restrict__ fc2_W,    // [64, 16]
    const float* __restrict__ fc2_b,    // [16]
    const float* __restrict__ ent_emb,
    const int* __restrict__ v,
    float* __restrict__ out)            // [B, 17]
{
    __shared__ float sm[S][D + 1];
    __shared__ float fus[2 * D];
    __shared__ float hid[64];
    __shared__ float feat_s[D];

    int b = blockIdx.x, t = threadIdx.x;   // 64 threads, t = s index
    const float4* ip = (const float4*)(item + ((long)b * S + t) * D);
    float4 r0 = ip[0], r1 = ip[1], r2 = ip[2], r3 = ip[3];
    sm[t][0] = r0.x;  sm[t][1] = r0.y;  sm[t][2] = r0.z;  sm[t][3] = r0.w;
    sm[t][4] = r1.x;  sm[t][5] = r1.y;  sm[t][6] = r1.z;  sm[t][7] = r1.w;
    sm[t][8] = r2.x;  sm[t][9] = r2.y;  sm[t][10] = r2.z; sm[t][11] = r2.w;
    sm[t][12] = r3.x; sm[t][13] = r3.y; sm[t][14] = r3.z; sm[t][15] = r3.w;
    __syncthreads();

    if (t < D) {
        float sv = 0.0f, mv = -1e30f;
        for (int ss = 0; ss < S; ++ss) {
            float x = sm[ss][t];
            sv += x;
            mv = fmaxf(mv, x);
        }
        fus[t] = fmaxf(sv, 0.0f);
        fus[D + t] = fmaxf(mv, 0.0f);
    }
    __syncthreads();

    // fc1: hid[t] = relu(fus @ fc1_W[:,t] + b)
    float a = fc1_b[t];
#pragma unroll
    for (int i = 0; i < 2 * D; ++i) a += fus[i] * fc1_W[i * 64 + t];
    hid[t] = fmaxf(a, 0.0f);
    __syncthreads();

    if (t < D) {
        float f = fc2_b[t];
#pragma unroll
        for (int i = 0; i < 64; ++i) f += hid[i] * fc2_W[i * D + t];
        feat_s[t] = fmaxf(f, 0.0f);
    }
    __syncthreads();

    if (t < D) {
        float g = feat_s[t] * ent_emb[(long)v[b] * D + t];
        g += __shfl_xor(g, 1);
        g += __shfl_xor(g, 2);
        g += __shfl_xor(g, 4);
        g += __shfl_xor(g, 8);
        if (t == 0) out[(long)b * 17] = 1.0f / (1.0f + expf(-g));
    }
}

// ---------------------------------------------------------------------------
// Diffusion MLP: x0 -> 128 -> 128 -> 128 -> 16, one block (128 thr) per sample
// ---------------------------------------------------------------------------
__global__ __launch_bounds__(128) void k_diff(
    const float* __restrict__ usr_emb, const float* __restrict__ noise_e,
    const int* __restrict__ u, const int* __restrict__ t_arr,
    const float* __restrict__ W1, const float* __restrict__ b1,
    const float* __restrict__ W2, const float* __restrict__ b2,
    const float* __restrict__ W3, const float* __restrict__ b3,
    const float* __restrict__ W4, const float* __restrict__ b4,
    const float* __restrict__ se1, const float* __restrict__ se2,
    const float* __restrict__ se3,
    const float* __restrict__ sa, const float* __restrict__ so,
    float* __restrict__ out)   // [B, 17]
{
    __shared__ float x0[D];
    __shared__ float ha[NUNITS];
    __shared__ float hb[NUNITS];

    int b = blockIdx.x, t = threadIdx.x;
    int ts = t_arr[b];
    if (t < D) {
        x0[t] = usr_emb[(long)u[b] * D + t] * sa[ts] + noise_e[(long)b * D + t] * so[ts];
    }
    __syncthreads();

    // layer 1
    float a = b1[t] + se1[(long)ts * NUNITS + t];
#pragma unroll
    for (int i = 0; i < D; ++i) a += x0[i] * W1[i * NUNITS + t];
    ha[t] = fmaxf(a, 0.0f);
    __syncthreads();

    // layer 2
    a = b2[t] + se2[(long)ts * NUNITS + t];
    for (int i = 0; i < NUNITS; ++i) a += ha[i] * W2[i * NUNITS + t];
    hb[t] = fmaxf(a, 0.0f);
    __syncthreads();

    // layer 3
    a = b3[t] + se3[(long)ts * NUNITS + t];
    for (int i = 0; i < NUNITS; ++i) a += hb[i] * W3[i * NUNITS + t];
    __syncthreads();
    ha[t] = fmaxf(a, 0.0f);
    __syncthreads();

    // layer 4: 16 outputs
    if (t < D) {
        float acc = b4[t];
        for (int i = 0; i < NUNITS; ++i) acc += ha[i] * W4[i * D + t];
        out[(long)b * 17 + 1 + t] = acc;
    }
}

// ---------------------------------------------------------------------------
extern "C" void kernel_launch(void* const* d_in, const int* in_sizes, int n_in,
                              void* d_out, int out_size, void* d_ws, size_t ws_size,
                              hipStream_t stream) {
    const float* usr_emb = (const float*)d_in[0];
    const float* ent_emb = (const float*)d_in[1];
    const float* rel_emb = (const float*)d_in[2];
    const float* agg_W   = (const float*)d_in[3];
    const float* agg_b   = (const float*)d_in[4];
    const float* fc1_W   = (const float*)d_in[5];
    const float* fc1_b   = (const float*)d_in[6];
    const float* fc2_W   = (const float*)d_in[7];
    const float* fc2_b   = (const float*)d_in[8];
    const float* mlp_W1  = (const float*)d_in[9];
    const float* mlp_b1  = (const float*)d_in[10];
    const float* mlp_W2  = (const float*)d_in[11];
    const float* mlp_b2  = (const float*)d_in[12];
    const float* mlp_W3  = (const float*)d_in[13];
    const float* mlp_b3  = (const float*)d_in[14];
    const float* mlp_W4  = (const float*)d_in[15];
    const float* mlp_b4  = (const float*)d_in[16];
    const float* se1     = (const float*)d_in[17];
    const float* se2     = (const float*)d_in[18];
    const float* se3     = (const float*)d_in[19];
    const float* noise_e = (const float*)d_in[20];
    const int* u         = (const int*)d_in[21];
    const int* v         = (const int*)d_in[22];
    const int* click_seq = (const int*)d_in[23];
    const int* adj_ent   = (const int*)d_in[24];
    const int* adj_rel   = (const int*)d_in[25];
    const int* t         = (const int*)d_in[26];
    float* out = (float*)d_out;

    float* ws = (float*)d_ws;
    float* w_tab = ws;                 // B*NR floats
    float* sa    = w_tab + B * NR;     // 128 floats (NSTEPS used)
    float* so    = sa + 128;           // 128 floats
    float* item  = so + 128;           // B*S*D floats

    k_sched<<<1, 128, 0, stream>>>(sa, so);
    k_userrel<<<B, NR, 0, stream>>>(usr_emb, rel_emb, u, w_tab);
    k_kgcn<<<(B * S) / 4, 256, 0, stream>>>(ent_emb, w_tab, click_seq, adj_ent, adj_rel,
                                            agg_W, agg_b, item);
    k_fuse<<<B, 64, 0, stream>>>(item, fc1_W, fc1_b, fc2_W, fc2_b, ent_emb, v, out);
    k_diff<<<B, NUNITS, 0, stream>>>(usr_emb, noise_e, u, t, mlp_W1, mlp_b1, mlp_W2, mlp_b2,
                                     mlp_W3, mlp_b3, mlp_W4, mlp_b4, se1, se2, se3, sa, so, out);
}